// Round 1
// baseline (164.370 us; speedup 1.0000x reference)
//
#include <hip/hip_runtime.h>

// Sizes (fixed by the problem):
// pc1_0: [8,2048,3] -> 16384 pts   d_in[0]
// pc1_1: [8, 512,3] ->  4096 pts   d_in[1]
// pc1_3: [8, 256,1] ->  2048 vals  d_in[2]
// pc2  : [8,2048,3] -> 16384 pts   d_in[3]
// pc3  : [8, 256,3] ->  2048 pts   d_in[4]
//
// ws layout (floats):
//   [0      ,16384) minA0  : per pc1_0 point, min d2 to pc2      (cd, a->b)
//   [16384  ,32768) minB0  : per pc2   point, min d2 to pc1_0    (cd, b->a)
//   [32768  ,36864) minA1  : per pc1_1 point, min d2 to pc2      (seed, a->b)
//   [36864  ,53248) minB1  : per pc2   point, min d2 to pc1_1    (seed, b->a)
//   [53248  ,55296) minC   : per (b,i) pc3 point, min d2 to pc2[b] (confidence)
//   [55296  ,55304) acc[8] : partial sums

#define N_MINS 55296

__device__ __forceinline__ float blockReduceSum(float v, float* sbuf) {
#pragma unroll
  for (int off = 32; off > 0; off >>= 1) v += __shfl_down(v, off, 64);
  int lane = threadIdx.x & 63;
  int wid  = threadIdx.x >> 6;
  if (lane == 0) sbuf[wid] = v;
  __syncthreads();
  float r = 0.f;
  if (threadIdx.x == 0) r = sbuf[0] + sbuf[1] + sbuf[2] + sbuf[3];
  return r;
}

// Fused nearest-neighbor min kernel: 4 jobs decoded from blockIdx.x.
// Each block: 1024 A-points (4 per thread), one 1024-point B slice,
// B staged through LDS in 256-point float4 tiles (broadcast reads).
__global__ __launch_bounds__(256) void k_nn_all(
    const float* __restrict__ pc10, const float* __restrict__ pc11,
    const float* __restrict__ pc2, float* __restrict__ ws) {
  const float* A;
  const float* B;
  float* outMin;
  int aChunk, bStart;
  int blk = blockIdx.x;
  if (blk < 256) {            // job1: pc1_0 (16384) -> pc2 (16384)
    A = pc10; B = pc2; outMin = ws + 0;
    aChunk = blk >> 4; bStart = (blk & 15) * 1024;
  } else if (blk < 512) {     // job2: pc2 (16384) -> pc1_0 (16384)
    int j = blk - 256;
    A = pc2; B = pc10; outMin = ws + 16384;
    aChunk = j >> 4; bStart = (j & 15) * 1024;
  } else if (blk < 576) {     // job3: pc1_1 (4096) -> pc2 (16384)
    int j = blk - 512;
    A = pc11; B = pc2; outMin = ws + 32768;
    aChunk = j >> 4; bStart = (j & 15) * 1024;
  } else {                    // job4: pc2 (16384) -> pc1_1 (4096)
    int j = blk - 576;
    A = pc2; B = pc11; outMin = ws + 36864;
    aChunk = j >> 2; bStart = (j & 3) * 1024;
  }

  const int tid = threadIdx.x;
  __shared__ float4 tile[256];

  float ax[4], ay[4], az[4], mn[4];
#pragma unroll
  for (int r = 0; r < 4; ++r) {
    int ai = aChunk * 1024 + r * 256 + tid;
    ax[r] = A[ai * 3 + 0];
    ay[r] = A[ai * 3 + 1];
    az[r] = A[ai * 3 + 2];
    mn[r] = 3.0e38f;
  }

  for (int t0 = 0; t0 < 1024; t0 += 256) {
    __syncthreads();
    int bi = bStart + t0 + tid;
    tile[tid] = make_float4(B[bi * 3 + 0], B[bi * 3 + 1], B[bi * 3 + 2], 0.f);
    __syncthreads();
#pragma unroll 4
    for (int j = 0; j < 256; ++j) {
      float4 bp = tile[j];
#pragma unroll
      for (int r = 0; r < 4; ++r) {
        float dx = ax[r] - bp.x;
        float dy = ay[r] - bp.y;
        float dz = az[r] - bp.z;
        float d2 = dx * dx + dy * dy + dz * dz;
        mn[r] = fminf(mn[r], d2);
      }
    }
  }

#pragma unroll
  for (int r = 0; r < 4; ++r) {
    int ai = aChunk * 1024 + r * 256 + tid;
    atomicMin((unsigned int*)(outMin + ai), __float_as_uint(fmaxf(mn[r], 0.f)));
  }
}

// Confidence mins: per batch b (8), per pc3 point i (256), min d2 vs pc2[b] (2048).
// Grid: 8 batches x 8 slices of 256 pc2 points. One LDS tile per block.
__global__ __launch_bounds__(256) void k_conf_min(
    const float* __restrict__ pc3, const float* __restrict__ pc2,
    float* __restrict__ minC) {
  int b = blockIdx.x >> 3;
  int s = blockIdx.x & 7;
  int tid = threadIdx.x;
  __shared__ float4 tile[256];

  int i = b * 256 + tid;
  float px = pc3[i * 3 + 0];
  float py = pc3[i * 3 + 1];
  float pz = pc3[i * 3 + 2];

  int bi = b * 2048 + s * 256 + tid;
  tile[tid] = make_float4(pc2[bi * 3 + 0], pc2[bi * 3 + 1], pc2[bi * 3 + 2], 0.f);
  __syncthreads();

  float mn = 3.0e38f;
#pragma unroll 4
  for (int j = 0; j < 256; ++j) {
    float4 bp = tile[j];
    float dx = px - bp.x;
    float dy = py - bp.y;
    float dz = pz - bp.z;
    float d2 = dx * dx + dy * dy + dz * dz;
    mn = fminf(mn, d2);
  }
  atomicMin((unsigned int*)(minC + i), __float_as_uint(fmaxf(mn, 0.f)));
}

// Segmented reduce over [0, 55296+49152): sqrt-sums of the 4 chamfer min
// arrays, confidence squared-error, and point2point squared-error.
__global__ __launch_bounds__(256) void k_reduce(
    const float* __restrict__ ws, const float* __restrict__ pc13,
    const float* __restrict__ pc10, const float* __restrict__ pc2,
    float* __restrict__ acc) {
  __shared__ float sbuf[4];
  int idx = blockIdx.x * 256 + threadIdx.x;
  float v;
  int k;
  if (idx < 53248) {
    v = sqrtf(fmaxf(ws[idx], 0.f));
    k = (idx < 16384) ? 0 : (idx < 32768) ? 1 : (idx < 36864) ? 2 : 3;
  } else if (idx < 55296) {
    int i = idx - 53248;
    float score = expf(-sqrtf(fmaxf(ws[idx], 0.f)));
    float d = pc13[i] - score;
    v = d * d;
    k = 4;
  } else {
    int i = idx - 55296;
    float d = pc10[i] - pc2[i];
    v = d * d;
    k = 5;
  }
  float s = blockReduceSum(v, sbuf);
  if (threadIdx.x == 0) atomicAdd(acc + k, s);
}

__global__ void k_final(const float* __restrict__ acc, float* __restrict__ out) {
  float cd   = (acc[0] + acc[1]) * (1.f / 16384.f);
  float seed = acc[2] * (1.f / 4096.f) + acc[3] * (1.f / 16384.f);
  float conf = acc[4] * (1.f / 2048.f);
  float p2p  = acc[5] * (1.f / 49152.f);
  out[0] = 0.5f * cd + 0.5f * seed + 0.5f * conf + p2p;
}

extern "C" void kernel_launch(void* const* d_in, const int* in_sizes, int n_in,
                              void* d_out, int out_size, void* d_ws, size_t ws_size,
                              hipStream_t stream) {
  const float* pc10 = (const float*)d_in[0];
  const float* pc11 = (const float*)d_in[1];
  const float* pc13 = (const float*)d_in[2];
  const float* pc2  = (const float*)d_in[3];
  const float* pc3  = (const float*)d_in[4];
  float* ws  = (float*)d_ws;
  float* acc = ws + N_MINS;
  float* out = (float*)d_out;

  // init: min arrays to ~3.39e38 (0x7F7F7F7F), accumulators to 0
  hipMemsetAsync(ws, 0x7F, N_MINS * sizeof(float), stream);
  hipMemsetAsync(acc, 0, 8 * sizeof(float), stream);

  k_nn_all<<<640, 256, 0, stream>>>(pc10, pc11, pc2, ws);
  k_conf_min<<<64, 256, 0, stream>>>(pc3, pc2, ws + 53248);

  int reduce_blocks = (N_MINS + 49152) / 256;  // 408
  k_reduce<<<reduce_blocks, 256, 0, stream>>>(ws, pc13, pc10, pc2, acc);
  k_final<<<1, 1, 0, stream>>>(acc, out);
}

// Round 2
// 75.742 us; speedup vs baseline: 2.1701x; 2.1701x over previous
//
#include <hip/hip_runtime.h>

// Sizes (fixed by the problem):
// pc1_0: [8,2048,3] -> 16384 pts   d_in[0]
// pc1_1: [8, 512,3] ->  4096 pts   d_in[1]
// pc1_3: [8, 256,1] ->  2048 vals  d_in[2]
// pc2  : [8,2048,3] -> 16384 pts   d_in[3]
// pc3  : [8, 256,3] ->  2048 pts   d_in[4]
//
// ws layout (floats):
//   [0      ,16384) minA0  : per pc1_0 point, min d2 to pc2      (cd, a->b)
//   [16384  ,32768) minB0  : per pc2   point, min d2 to pc1_0    (cd, b->a)
//   [32768  ,36864) minA1  : per pc1_1 point, min d2 to pc2      (seed, a->b)
//   [36864  ,53248) minB1  : per pc2   point, min d2 to pc1_1    (seed, b->a)
//   [53248  ,55296) minC   : per (b,i) pc3 point, min d2 to pc2[b] (confidence)
//   [55296  ,55304) acc[8] : partial sums

#define N_MINS 55296
#define R 8  // A-points per thread

__device__ __forceinline__ float blockReduceSum(float v, float* sbuf) {
#pragma unroll
  for (int off = 32; off > 0; off >>= 1) v += __shfl_down(v, off, 64);
  int lane = threadIdx.x & 63;
  int wid  = threadIdx.x >> 6;
  if (lane == 0) sbuf[wid] = v;
  __syncthreads();
  float r = 0.f;
  if (threadIdx.x == 0) r = sbuf[0] + sbuf[1] + sbuf[2] + sbuf[3];
  return r;
}

// Fused NN-min kernel. Inner pair cost: 3 fma + 1 min, via
// d2 = |a|^2 + (|b|^2 - 2 a.b), with |a|^2 folded in after the min.
// Tile holds (-2bx, -2by, -2bz, |b|^2). Block = 256 thr x R=8 A-points,
// one 256-point B tile per block, partial mins merged with atomicMin
// (valid: values clamped >= 0 before the u32-bitwise min).
__global__ __launch_bounds__(256) void k_nn_all(
    const float* __restrict__ pc10, const float* __restrict__ pc11,
    const float* __restrict__ pc2, const float* __restrict__ pc3,
    float* __restrict__ ws) {
  const int tid = threadIdx.x;
  const int blk = blockIdx.x;
  __shared__ float4 tile[256];

  if (blk >= 1280) {  // confidence job: per-batch NN pc3[b] -> pc2[b]
    int j = blk - 1280;
    int b = j >> 3;
    int s = j & 7;
    int bi = b * 2048 + s * 256 + tid;
    {
      float bx = pc2[bi * 3 + 0], by = pc2[bi * 3 + 1], bz = pc2[bi * 3 + 2];
      tile[tid] = make_float4(-2.f * bx, -2.f * by, -2.f * bz,
                              bx * bx + by * by + bz * bz);
    }
    int i = b * 256 + tid;
    float ax = pc3[i * 3 + 0], ay = pc3[i * 3 + 1], az = pc3[i * 3 + 2];
    float ra = ax * ax + ay * ay + az * az;
    __syncthreads();
    float mn = 3.0e38f;
#pragma unroll 4
    for (int t = 0; t < 256; ++t) {
      float4 q = tile[t];
      float v = fmaf(q.x, ax, fmaf(q.y, ay, fmaf(q.z, az, q.w)));
      mn = fminf(mn, v);
    }
    atomicMin((unsigned int*)(ws + 53248 + i), __float_as_uint(fmaxf(mn + ra, 0.f)));
    return;
  }

  const float* A;
  const float* B;
  float* outMin;
  int aBase, bBase;
  if (blk < 512) {            // job1: pc1_0 (16384) -> pc2 (16384)
    A = pc10; B = pc2; outMin = ws + 0;
    aBase = (blk >> 6) * 2048; bBase = (blk & 63) * 256;
  } else if (blk < 1024) {    // job2: pc2 (16384) -> pc1_0 (16384)
    int j = blk - 512;
    A = pc2; B = pc10; outMin = ws + 16384;
    aBase = (j >> 6) * 2048; bBase = (j & 63) * 256;
  } else if (blk < 1152) {    // job3: pc1_1 (4096) -> pc2 (16384)
    int j = blk - 1024;
    A = pc11; B = pc2; outMin = ws + 32768;
    aBase = (j >> 6) * 2048; bBase = (j & 63) * 256;
  } else {                    // job4: pc2 (16384) -> pc1_1 (4096)
    int j = blk - 1152;
    A = pc2; B = pc11; outMin = ws + 36864;
    aBase = (j >> 4) * 2048; bBase = (j & 15) * 256;
  }

  // stage B tile as (-2b, |b|^2)
  {
    int bi = bBase + tid;
    float bx = B[bi * 3 + 0], by = B[bi * 3 + 1], bz = B[bi * 3 + 2];
    tile[tid] = make_float4(-2.f * bx, -2.f * by, -2.f * bz,
                            bx * bx + by * by + bz * bz);
  }

  float ax[R], ay[R], az[R], mn[R];
#pragma unroll
  for (int r = 0; r < R; ++r) {
    int ai = aBase + r * 256 + tid;
    ax[r] = A[ai * 3 + 0];
    ay[r] = A[ai * 3 + 1];
    az[r] = A[ai * 3 + 2];
    mn[r] = 3.0e38f;
  }
  __syncthreads();

#pragma unroll 4
  for (int t = 0; t < 256; ++t) {
    float4 q = tile[t];
#pragma unroll
    for (int r = 0; r < R; ++r) {
      float v = fmaf(q.x, ax[r], fmaf(q.y, ay[r], fmaf(q.z, az[r], q.w)));
      mn[r] = fminf(mn[r], v);
    }
  }

#pragma unroll
  for (int r = 0; r < R; ++r) {
    int ai = aBase + r * 256 + tid;
    float ra = fmaf(ax[r], ax[r], fmaf(ay[r], ay[r], az[r] * az[r]));
    atomicMin((unsigned int*)(outMin + ai),
              __float_as_uint(fmaxf(mn[r] + ra, 0.f)));
  }
}

// Segmented reduce: sqrt-sums of the 4 chamfer min arrays, confidence
// squared-error, and point2point squared-error.
__global__ __launch_bounds__(256) void k_reduce(
    const float* __restrict__ ws, const float* __restrict__ pc13,
    const float* __restrict__ pc10, const float* __restrict__ pc2,
    float* __restrict__ acc) {
  __shared__ float sbuf[4];
  int idx = blockIdx.x * 256 + threadIdx.x;
  float v;
  int k;
  if (idx < 53248) {
    v = sqrtf(fmaxf(ws[idx], 0.f));
    k = (idx < 16384) ? 0 : (idx < 32768) ? 1 : (idx < 36864) ? 2 : 3;
  } else if (idx < 55296) {
    int i = idx - 53248;
    float score = expf(-sqrtf(fmaxf(ws[idx], 0.f)));
    float d = pc13[i] - score;
    v = d * d;
    k = 4;
  } else {
    int i = idx - 55296;
    float d = pc10[i] - pc2[i];
    v = d * d;
    k = 5;
  }
  float s = blockReduceSum(v, sbuf);
  if (threadIdx.x == 0) atomicAdd(acc + k, s);
}

__global__ void k_final(const float* __restrict__ acc, float* __restrict__ out) {
  float cd   = (acc[0] + acc[1]) * (1.f / 16384.f);
  float seed = acc[2] * (1.f / 4096.f) + acc[3] * (1.f / 16384.f);
  float conf = acc[4] * (1.f / 2048.f);
  float p2p  = acc[5] * (1.f / 49152.f);
  out[0] = 0.5f * cd + 0.5f * seed + 0.5f * conf + p2p;
}

extern "C" void kernel_launch(void* const* d_in, const int* in_sizes, int n_in,
                              void* d_out, int out_size, void* d_ws, size_t ws_size,
                              hipStream_t stream) {
  const float* pc10 = (const float*)d_in[0];
  const float* pc11 = (const float*)d_in[1];
  const float* pc13 = (const float*)d_in[2];
  const float* pc2  = (const float*)d_in[3];
  const float* pc3  = (const float*)d_in[4];
  float* ws  = (float*)d_ws;
  float* acc = ws + N_MINS;
  float* out = (float*)d_out;

  // init: min arrays to ~3.39e38 (0x7F7F7F7F), accumulators to 0
  hipMemsetAsync(ws, 0x7F, N_MINS * sizeof(float), stream);
  hipMemsetAsync(acc, 0, 8 * sizeof(float), stream);

  k_nn_all<<<1344, 256, 0, stream>>>(pc10, pc11, pc2, pc3, ws);

  int reduce_blocks = (N_MINS + 49152) / 256;  // 408
  k_reduce<<<reduce_blocks, 256, 0, stream>>>(ws, pc13, pc10, pc2, acc);
  k_final<<<1, 1, 0, stream>>>(acc, out);
}